// Round 14
// baseline (519.545 us; speedup 1.0000x reference)
//
#include <hip/hip_runtime.h>
#include <cstddef>
#include <cstdint>

constexpr int Bn    = 8;
constexpr int Hn    = 96;
constexpr int Wn    = 96;
constexpr int HWn   = Hn * Wn;       // 9216
constexpr int BHWn  = Bn * HWn;      // 73728
constexpr int B10HW = Bn * 10 * HWn; // 737280

// packed-activation geometry (bf16, halo-padded, 8-channel-interleaved)
constexpr int XP_COLS        = 100;
constexpr int XP_ROWS        = 100;
constexpr int XP_PLANE       = XP_ROWS * XP_COLS; // 10000 16B groups
constexpr int XP_PLANE_BYTES = XP_PLANE * 16;     // 160000
constexpr int XP_OCT         = 36;                // 288 padded channels / 8

using short8  = __attribute__((ext_vector_type(8))) short;
using ushort8 = __attribute__((ext_vector_type(8))) unsigned short;
using float4v = __attribute__((ext_vector_type(4))) float;

__device__ __forceinline__ unsigned short f2bf(float f) {
    unsigned u = __builtin_bit_cast(unsigned, f);
    u += 0x7FFFu + ((u >> 16) & 1u);   // RNE; inputs are finite
    return (unsigned short)(u >> 16);
}

// async global->LDS: 16B per lane, LDS dest = uniform base + lane*16
__device__ __forceinline__ void async16(const void* g, void* l) {
    auto gp = (__attribute__((address_space(1))) unsigned int*)(uintptr_t)g;
    auto lp = (__attribute__((address_space(3))) unsigned int*)(unsigned)(uintptr_t)l;
    __builtin_amdgcn_global_load_lds(gp, lp, 16, 0, 0);
}

struct BranchW  { const float *w1, *g1, *b1, *w2, *g2, *b2; };
struct BranchW3 { BranchW p[3]; };

// shared-memory layouts for the fused kernel paths
struct ConvSmem   { short xs[3][4][194][8]; float part[4][64][2]; };   // 39.3 KB
struct BranchSmem {
    float xt[20][10][34];
    float paSum[340];
    float wlt[9 * 20 * 12];
    float w2l[100], g1l[10], b1l[10], g2l[10], b2l[10];
};                                                                      // 37.8 KB
struct GruSmem    { float gwl[40], cwl[200], gbl[2], cgl[10], cbl[10]; };
union FusedSmem { ConvSmem c; BranchSmem b; GruSmem g; };

// ---------------------------------------------------------------------------
// K0 (merged): bx<2592 -> pack da_w1 into B-fragment order (bf16 wpk);
// bx>=2592 -> pack activations to bf16 halo-padded xp.
// ---------------------------------------------------------------------------
constexpr int PACKW_BLOCKS = 2592;

__global__ void k_pack(const float* __restrict__ w1, short* __restrict__ wpk,
                       const float* __restrict__ xh, const float* __restrict__ patt,
                       ushort* __restrict__ xp)
{
    if (blockIdx.x < PACKW_BLOCKS) {
        const int o = blockIdx.x * 256 + threadIdx.x;   // 663552 exactly
        const int j    = o & 7;
        const int lane = (o >> 3) & 63;
        const int q    = (o >> 9) & 15;
        const int t    = o >> 13;            // 0..80 = cb*9+tap
        const int co   = q * 16 + (lane & 15);
        const int ci   = (t / 9) * 32 + ((lane >> 4) & 3) * 8 + j;
        const int tap  = t % 9;
        const float f  = (ci < 257) ? w1[((size_t)co * 257 + ci) * 9 + tap] : 0.f;
        wpk[o] = (short)f2bf(f);
    } else {
        const int g  = (blockIdx.x - PACKW_BLOCKS) * 256 + threadIdx.x; // 2,880,000
        const int cw = g % XP_COLS;
        int t = g / XP_COLS;
        const int rh = t % XP_ROWS; t /= XP_ROWS;
        const int o  = t % XP_OCT;
        const int b  = t / XP_OCT;
        const int hh = rh - 1, ww = cw - 1;
        const bool inb = ((unsigned)hh < (unsigned)Hn) & ((unsigned)ww < (unsigned)Wn);
        const int off = hh * Wn + ww;
        ushort8 v;
        #pragma unroll
        for (int j = 0; j < 8; ++j) {
            const int ci = o * 8 + j;
            float f = 0.f;
            if (inb && ci < 257)
                f = (ci == 0) ? patt[b * HWn + off]
                              : xh[((size_t)b * 256 + (ci - 1)) * HWn + off];
            v[j] = f2bf(f);
        }
        *(ushort8*)&xp[(size_t)g * 8] = v;
    }
}

// standalone packw for the fallback (no-xp) path
__global__ void k_packw(const float* __restrict__ w1, short* __restrict__ wpk)
{
    const int o = blockIdx.x * 256 + threadIdx.x;
    if (o >= 663552) return;
    const int j    = o & 7;
    const int lane = (o >> 3) & 63;
    const int q    = (o >> 9) & 15;
    const int t    = o >> 13;
    const int co   = q * 16 + (lane & 15);
    const int ci   = (t / 9) * 32 + ((lane >> 4) & 3) * 8 + j;
    const int tap  = t % 9;
    const float f  = (ci < 257) ? w1[((size_t)co * 257 + ci) * 9 + tap] : 0.f;
    wpk[o] = (short)f2bf(f);
}

// ---------------------------------------------------------------------------
// Branch body: ReLU(BN(conv3x3 20->10)) -> ReLU(BN(conv1x1 10->10)).
// z=0/1: [parent*s01, h] (rel). z=2/3: [h, composed parts] (cu/cl).
// ---------------------------------------------------------------------------
__device__ __forceinline__ void branch_body(
    BranchSmem& S, int z, int bx, int tid, const BranchW3& P,
    const float* __restrict__ parent, const float* __restrict__ h_nodes,
    const float* __restrict__ s01, const float* __restrict__ pn,
    const float* __restrict__ pa, float* __restrict__ bout)
{
    const int pi = (z < 2) ? 0 : (z - 1);
    const BranchW& Pw = P.p[pi];
    for (int idx = tid; idx < 2160; idx += 256) {
        const int co = idx % 12, rem = idx / 12, ci = rem % 20, tap = rem / 20;
        S.wlt[idx] = (co < 10) ? Pw.w1[(co * 20 + ci) * 9 + tap] : 0.f;
    }
    if (tid < 100) S.w2l[tid] = Pw.w2[tid];
    if (tid < 10) {
        S.g1l[tid] = Pw.g1[tid]; S.b1l[tid] = Pw.b1[tid];
        S.g2l[tid] = Pw.g2[tid]; S.b2l[tid] = Pw.b2[tid];
    }

    const int tw = bx % 3, th = (bx / 3) % 12, b = bx / 36;
    const int h0 = th * 8, w0 = tw * 32;

    const float* Ab;
    const float* sc = nullptr;
    const float* Bb = nullptr;
    int k0 = 0, k1 = -1;
    if (z == 0)      { Ab = parent; sc = s01;        Bb = h_nodes + (size_t)1 * B10HW; }
    else if (z == 1) { Ab = parent; sc = s01 + BHWn; Bb = h_nodes + (size_t)2 * B10HW; }
    else if (z == 2) { Ab = h_nodes + (size_t)1 * B10HW; k0 = 1; k1 = 4; }
    else             { Ab = h_nodes + (size_t)2 * B10HW; k0 = 5; k1 = 6; }

    if (z >= 2) {
        for (int idx = tid; idx < 340; idx += 256) {
            const int col = idx % 34, row = idx / 34;
            const int hh = h0 - 1 + row, ww = w0 - 1 + col;
            float s = 0.f;
            if (((unsigned)hh < (unsigned)Hn) & ((unsigned)ww < (unsigned)Wn)) {
                const int off = hh * Wn + ww;
                for (int k = k0; k <= k1; ++k)
                    s += pa[(size_t)(k * Bn + b) * HWn + off];
            }
            S.paSum[idx] = s;
        }
    }
    __syncthreads();

    for (int idx = tid; idx < 6800; idx += 256) {
        const int col = idx % 34, rem = idx / 34, row = rem % 10, ch = rem / 10;
        const int hh = h0 - 1 + row, ww = w0 - 1 + col;
        float v = 0.f;
        if (((unsigned)hh < (unsigned)Hn) & ((unsigned)ww < (unsigned)Wn)) {
            const int off = hh * Wn + ww;
            if (ch < 10) {
                v = Ab[((size_t)b * 10 + ch) * HWn + off];
                if (sc) v *= sc[b * HWn + off];
            } else if (z < 2) {
                v = Bb[((size_t)b * 10 + (ch - 10)) * HWn + off];
            } else {
                float s = 0.f;
                for (int k = k0; k <= k1; ++k)
                    s += pn[((size_t)(k * Bn + b) * 10 + (ch - 10)) * HWn + off];
                v = s * S.paSum[row * 34 + col];
            }
        }
        ((float*)S.xt)[idx] = v;
    }
    __syncthreads();

    const int r = tid >> 5, c = tid & 31;
    float a0 = 0, a1 = 0, a2 = 0, a3 = 0, a4 = 0, a5 = 0, a6 = 0, a7 = 0, a8 = 0, a9 = 0;
    #pragma unroll
    for (int tap = 0; tap < 9; ++tap) {
        const int kh = tap / 3, kw = tap % 3;
        #pragma unroll
        for (int ci = 0; ci < 20; ++ci) {
            const float xv = S.xt[ci][r + kh][c + kw];
            const float4 wA = *(const float4*)&S.wlt[(tap * 20 + ci) * 12];
            const float4 wB = *(const float4*)&S.wlt[(tap * 20 + ci) * 12 + 4];
            const float2 wC = *(const float2*)&S.wlt[(tap * 20 + ci) * 12 + 8];
            a0 = fmaf(wA.x, xv, a0); a1 = fmaf(wA.y, xv, a1);
            a2 = fmaf(wA.z, xv, a2); a3 = fmaf(wA.w, xv, a3);
            a4 = fmaf(wB.x, xv, a4); a5 = fmaf(wB.y, xv, a5);
            a6 = fmaf(wB.z, xv, a6); a7 = fmaf(wB.w, xv, a7);
            a8 = fmaf(wC.x, xv, a8); a9 = fmaf(wC.y, xv, a9);
        }
    }
    float acc[10] = {a0, a1, a2, a3, a4, a5, a6, a7, a8, a9};
    float y[10];
    #pragma unroll
    for (int co = 0; co < 10; ++co)
        y[co] = fmaxf(fmaf(acc[co], S.g1l[co], S.b1l[co]), 0.f);
    const int hw = (h0 + r) * Wn + (w0 + c);
    #pragma unroll
    for (int co = 0; co < 10; ++co) {
        float s = 0.f;
        #pragma unroll
        for (int i = 0; i < 10; ++i) s = fmaf(S.w2l[co * 10 + i], y[i], s);
        s = fmaxf(fmaf(s, S.g2l[co], S.b2l[co]), 0.f);
        bout[(size_t)z * B10HW + ((size_t)b * 10 + co) * HWn + hw] = s;
    }
}

// ---------------------------------------------------------------------------
// GRU body (1x1 ConvGRU), z = node 0/1/2.
// ---------------------------------------------------------------------------
__device__ __forceinline__ void gru_body(
    GruSmem& S, int z, int bx, int tid,
    const float* __restrict__ f_nodes, const float* __restrict__ h_nodes,
    const float* __restrict__ p_nodes, const float* __restrict__ bout,
    const float* __restrict__ gw, const float* __restrict__ gb,
    const float* __restrict__ cw, const float* __restrict__ cg,
    const float* __restrict__ cb, float* __restrict__ out)
{
    if (tid < 40)  S.gwl[tid] = gw[z * 40 + tid];
    if (tid < 200) S.cwl[tid] = cw[z * 200 + tid];
    if (tid < 2)   S.gbl[tid] = gb[z * 2 + tid];
    if (tid < 10) {
        S.cgl[tid] = cg[z * 10 + tid];
        S.cbl[tid] = cb[z * 10 + tid];
    }
    __syncthreads();

    const int p = bx * 256 + tid;
    const int b = p / HWn, hw = p % HWn;
    float x[10], h[10];
    #pragma unroll
    for (int c = 0; c < 10; ++c) {
        const size_t idx = ((size_t)b * 10 + c) * HWn + hw;
        if (z == 0)      x[c] = f_nodes[idx] + p_nodes[idx];
        else if (z == 1) x[c] = bout[(size_t)2 * B10HW + idx] + bout[idx];
        else             x[c] = bout[(size_t)3 * B10HW + idx] + bout[(size_t)1 * B10HW + idx];
        h[c] = h_nodes[(size_t)z * B10HW + idx];
    }
    float g0 = S.gbl[0], g1 = S.gbl[1];
    #pragma unroll
    for (int c = 0; c < 10; ++c) {
        g0 = fmaf(S.gwl[c],      x[c], g0);
        g0 = fmaf(S.gwl[10 + c], h[c], g0);
        g1 = fmaf(S.gwl[20 + c], x[c], g1);
        g1 = fmaf(S.gwl[30 + c], h[c], g1);
    }
    const float r = 1.f / (1.f + expf(-g0));
    const float u = 1.f / (1.f + expf(-g1));
    #pragma unroll
    for (int o = 0; o < 10; ++o) {
        float s = 0.f;
        #pragma unroll
        for (int c = 0; c < 10; ++c) {
            s = fmaf(S.cwl[o * 20 + c],      x[c],     s);
            s = fmaf(S.cwl[o * 20 + 10 + c], r * h[c], s);
        }
        s = fmaxf(fmaf(s, S.cgl[o], S.cbl[o]), 0.f);
        out[(size_t)z * B10HW + ((size_t)b * 10 + o) * HWn + hw] =
            (1.f - u) * h[o] + u * s;
    }
}

// ---------------------------------------------------------------------------
// FUSED kernel (R8 structure): bx<1152 = conv, bx>=1152 = fillers appended.
// ONE change vs R13: __launch_bounds__(256, 4) — LDS (39.4 KB x 4 = 157.7 KB
// <= 160 KB) and VGPR (84 <= 128) both admit 4 blocks/CU; the (256,3) bound
// was the only thing capping residency at 3. 16 resident waves/CU give the
// scheduler more to run while barrier-parked waves wait on vmcnt(3).
// ---------------------------------------------------------------------------
constexpr int CONV_BLOCKS = 1152;

__global__ __launch_bounds__(256, 4)
void k_fused(const char* __restrict__ xp, const float* __restrict__ patt,
             const short* __restrict__ wpk, const float* __restrict__ g1,
             const float* __restrict__ b1, const float* __restrict__ w2,
             const float* __restrict__ db2,
             float* __restrict__ dm_out, float* __restrict__ s01,
             BranchW3 P, const float* __restrict__ parent,
             const float* __restrict__ h_nodes, const float* __restrict__ pn,
             const float* __restrict__ pa, float* __restrict__ bout,
             const float* __restrict__ f_nodes, const float* __restrict__ p_nodes,
             const float* __restrict__ gw, const float* __restrict__ gb,
             const float* __restrict__ cw, const float* __restrict__ cg,
             const float* __restrict__ cb, float* __restrict__ out)
{
    __shared__ __align__(16) FusedSmem sm;
    const int tid = threadIdx.x;
    const int bxg = blockIdx.x;

    if (bxg >= CONV_BLOCKS) {
        const int r = bxg - CONV_BLOCKS;
        if (r < 576) {
            const int z = (r < 288) ? 2 : 3;
            branch_body(sm.b, z, (r < 288) ? r : r - 288, tid, P, parent,
                        h_nodes, s01, pn, pa, bout);
        } else {
            gru_body(sm.g, 0, r - 576, tid, f_nodes, h_nodes, p_nodes, bout,
                     gw, gb, cw, cg, cb, out);
        }
        return;
    }

    const int lane = tid & 63;
    const int wid  = tid >> 6;          // wave id = n-quarter = staged octet
    const int bx   = bxg;
    const int b    = bx & 7;            // XCD-locality swizzle
    const int r2   = bx >> 3;
    const int wseg = r2 % 3;
    const int hb   = r2 / 3;
    const int h0   = hb * 2, w0 = wseg * 32;
    const int am   = lane & 15;
    const int aq   = lane >> 4;

    int poff[3];
    #pragma unroll
    for (int it = 0; it < 3; ++it) {
        const int pos = it * 64 + lane;
        const int row = pos / 34, col = pos - row * 34;
        poff[it] = ((h0 + row) * XP_COLS + (w0 + col)) * 16;
    }
    const char* xpb = xp + ((size_t)b * XP_OCT + wid) * XP_PLANE_BYTES;

    float4v acc[4][4];
    #pragma unroll
    for (int i = 0; i < 4; ++i)
        #pragma unroll
        for (int j = 0; j < 4; ++j)
            acc[i][j] = float4v{0.f, 0.f, 0.f, 0.f};

    int arow[4], acol[4];
    #pragma unroll
    for (int mt = 0; mt < 4; ++mt) {
        const int m = mt * 16 + am;
        arow[mt] = m >> 5;
        acol[mt] = m & 31;
    }

    auto stageX = [&](int cb, int buf) {
        const char* src = xpb + (size_t)cb * (4 * XP_PLANE_BYTES);
        #pragma unroll
        for (int it = 0; it < 3; ++it)
            async16(src + poff[it], &sm.c.xs[buf][wid][it * 64][0]);
    };

    const short8* wp = (const short8*)wpk;
    const int qb = wid * 4;

    auto loadB = [&](int t, short8 (&dst)[4]) {
        #pragma unroll
        for (int nt = 0; nt < 4; ++nt)
            dst[nt] = wp[((size_t)t * 16 + qb + nt) * 64 + lane];
    };

    // prologue: two chunks in flight, two B tiles in registers
    stageX(0, 0);
    stageX(1, 1);
    short8 bfr[3][4];
    loadB(0, bfr[0]);
    loadB(1, bfr[1]);

    for (int cb = 0; cb < 9; ++cb) {
        __builtin_amdgcn_sched_barrier(0);
        if (cb < 8) asm volatile("s_waitcnt vmcnt(3)" ::: "memory");
        else        asm volatile("s_waitcnt vmcnt(0)" ::: "memory");
        __builtin_amdgcn_s_barrier();
        __builtin_amdgcn_sched_barrier(0);
        if (cb < 7) stageX(cb + 2, (cb + 2) % 3);

        const int buf = cb % 3;
        #pragma unroll
        for (int tap = 0; tap < 9; ++tap) {
            const int t  = cb * 9 + tap;
            const int tl = (t + 2 <= 80) ? (t + 2) : 80;
            loadB(tl, bfr[(tap + 2) % 3]);
            const int kh = tap / 3, kw = tap % 3;
            short8 afr[4];
            #pragma unroll
            for (int mt = 0; mt < 4; ++mt) {
                const int pos = (arow[mt] + kh) * 34 + (acol[mt] + kw);
                afr[mt] = *(const short8*)&sm.c.xs[buf][aq][pos][0];
            }
            __builtin_amdgcn_s_setprio(1);
            #pragma unroll
            for (int mt = 0; mt < 4; ++mt)
                #pragma unroll
                for (int nt = 0; nt < 4; ++nt)
                    acc[mt][nt] = __builtin_amdgcn_mfma_f32_16x16x32_bf16(
                        afr[mt], bfr[tap % 3][nt], acc[mt][nt], 0, 0, 0);
            __builtin_amdgcn_s_setprio(0);
        }
    }

    float gv[4], bv[4], wa[4], wbv[4];
    #pragma unroll
    for (int nt = 0; nt < 4; ++nt) {
        const int co = wid * 64 + nt * 16 + am;
        gv[nt]  = g1[co];
        bv[nt]  = b1[co];
        wa[nt]  = w2[co];
        wbv[nt] = w2[256 + co];
    }
    #pragma unroll
    for (int mt = 0; mt < 4; ++mt) {
        #pragma unroll
        for (int reg = 0; reg < 4; ++reg) {
            float s0 = 0.f, s1 = 0.f;
            #pragma unroll
            for (int nt = 0; nt < 4; ++nt) {
                const float y = fmaxf(fmaf(acc[mt][nt][reg], gv[nt], bv[nt]), 0.f);
                s0 = fmaf(wa[nt], y, s0);
                s1 = fmaf(wbv[nt], y, s1);
            }
            #pragma unroll
            for (int off = 1; off < 16; off <<= 1) {
                s0 += __shfl_xor(s0, off, 64);
                s1 += __shfl_xor(s1, off, 64);
            }
            if (am == 0) {
                const int m = mt * 16 + aq * 4 + reg;
                sm.c.part[wid][m][0] = s0;
                sm.c.part[wid][m][1] = s1;
            }
        }
    }
    __syncthreads();
    if (tid < 64) {
        const int m = tid, r = m >> 5, c = m & 31;
        const int off = (h0 + r) * Wn + (w0 + c);
        float d0 = sm.c.part[0][m][0] + sm.c.part[1][m][0] + sm.c.part[2][m][0]
                 + sm.c.part[3][m][0] + db2[0];
        float d1 = sm.c.part[0][m][1] + sm.c.part[1][m][1] + sm.c.part[2][m][1]
                 + sm.c.part[3][m][1] + db2[1];
        dm_out[(size_t)(b * 2) * HWn + off]     = d0;
        dm_out[(size_t)(b * 2 + 1) * HWn + off] = d1;
        const float mx = fmaxf(d0, d1);
        const float e0 = expf(d0 - mx), e1 = expf(d1 - mx);
        const float pa2 = patt[b * HWn + off];
        const float inv = pa2 / (e0 + e1);
        s01[b * HWn + off]        = e0 * inv;
        s01[BHWn + b * HWn + off] = e1 * inv;
    }
}

// ---------------------------------------------------------------------------
// Remaining dependent work: branch z=0/1 (needs s01) and gru z=1/2 (needs bout)
// ---------------------------------------------------------------------------
__global__ __launch_bounds__(256)
void k_branch01(BranchW3 P, const float* __restrict__ parent,
                const float* __restrict__ h_nodes, const float* __restrict__ s01,
                const float* __restrict__ pn, const float* __restrict__ pa,
                float* __restrict__ bout)
{
    __shared__ __align__(16) BranchSmem S;
    branch_body(S, blockIdx.y, blockIdx.x, threadIdx.x, P, parent, h_nodes,
                s01, pn, pa, bout);
}

__global__ void k_gru12(const float* __restrict__ f_nodes, const float* __restrict__ h_nodes,
                        const float* __restrict__ p_nodes, const float* __restrict__ bout,
                        const float* __restrict__ gw, const float* __restrict__ gb,
                        const float* __restrict__ cw, const float* __restrict__ cg,
                        const float* __restrict__ cb, float* __restrict__ out)
{
    __shared__ GruSmem S;
    gru_body(S, blockIdx.y + 1, blockIdx.x, threadIdx.x, f_nodes, h_nodes,
             p_nodes, bout, gw, gb, cw, cg, cb, out);
}

// fallback-path full kernels
__global__ __launch_bounds__(256)
void k_branch_all(BranchW3 P, const float* __restrict__ parent,
                  const float* __restrict__ h_nodes, const float* __restrict__ s01,
                  const float* __restrict__ pn, const float* __restrict__ pa,
                  float* __restrict__ bout)
{
    __shared__ __align__(16) BranchSmem S;
    branch_body(S, blockIdx.y, blockIdx.x, threadIdx.x, P, parent, h_nodes,
                s01, pn, pa, bout);
}

__global__ void k_gru_all(const float* __restrict__ f_nodes, const float* __restrict__ h_nodes,
                          const float* __restrict__ p_nodes, const float* __restrict__ bout,
                          const float* __restrict__ gw, const float* __restrict__ gb,
                          const float* __restrict__ cw, const float* __restrict__ cg,
                          const float* __restrict__ cb, float* __restrict__ out)
{
    __shared__ GruSmem S;
    gru_body(S, blockIdx.y, blockIdx.x, threadIdx.x, f_nodes, h_nodes,
             p_nodes, bout, gw, gb, cw, cg, cb, out);
}

// ---------------------------------------------------------------------------
// K1 fallback (old staging path) — used only if ws_size can't hold xp.
// ---------------------------------------------------------------------------
__global__ __launch_bounds__(256, 3)
void k_bigconv3_f(const float* __restrict__ xh, const float* __restrict__ patt,
                  const short* __restrict__ wpk, const float* __restrict__ g1,
                  const float* __restrict__ b1, const float* __restrict__ w2,
                  const float* __restrict__ db2,
                  float* __restrict__ dm_out, float* __restrict__ s01)
{
    __shared__ __align__(16) short xs[2][4][137][8];
    __shared__ float part[4][64][2];

    const int tid  = threadIdx.x;
    const int lane = tid & 63;
    const int wid  = tid >> 6;
    const int bx   = blockIdx.x;
    const int b    = bx & 7;
    const int r2   = bx >> 3;
    const int wseg = r2 % 3;
    const int hb   = r2 / 3;
    const int h0   = hb * 2, w0 = wseg * 32;
    const int am   = lane & 15;
    const int aq   = lane >> 4;

    float4v acc[4][4];
    #pragma unroll
    for (int i = 0; i < 4; ++i)
        #pragma unroll
        for (int j = 0; j < 4; ++j)
            acc[i][j] = float4v{0.f, 0.f, 0.f, 0.f};

    int arow[4], acol[4];
    #pragma unroll
    for (int mt = 0; mt < 4; ++mt) {
        const int m = mt * 16 + am;
        arow[mt] = m >> 5;
        acol[mt] = m & 31;
    }

    auto stageX = [&](int cb, int buf) {
        const int cig0 = cb * 32 + wid * 8;
        for (int pos = lane; pos < 136; pos += 64) {
            const int row = pos / 34, col = pos % 34;
            const int hh = h0 - 1 + row, ww = w0 - 1 + col;
            const bool inb = ((unsigned)hh < (unsigned)Hn) & ((unsigned)ww < (unsigned)Wn);
            const int off = hh * Wn + ww;
            ushort8 v;
            #pragma unroll
            for (int j = 0; j < 8; ++j) {
                const int ci = cig0 + j;
                float f = 0.f;
                if (inb && ci < 257)
                    f = (ci == 0) ? patt[b * HWn + off]
                                  : xh[((size_t)b * 256 + (ci - 1)) * HWn + off];
                v[j] = f2bf(f);
            }
            *(ushort8*)&xs[buf][wid][pos][0] = v;
        }
    };

    const short8* wp = (const short8*)wpk;
    const int qb = wid * 4;

    stageX(0, 0);
    short8 bfr[4], bnx[4];
    #pragma unroll
    for (int nt = 0; nt < 4; ++nt)
        bfr[nt] = wp[(size_t)(qb + nt) * 64 + lane];
    __syncthreads();

    for (int cb = 0; cb < 9; ++cb) {
        const int buf = cb & 1;
        for (int tap = 0; tap < 9; ++tap) {
            const int t = cb * 9 + tap;
            if (t < 80) {
                #pragma unroll
                for (int nt = 0; nt < 4; ++nt)
                    bnx[nt] = wp[((size_t)(t + 1) * 16 + qb + nt) * 64 + lane];
            }
            const int kh = tap / 3, kw = tap % 3;
            short8 afr[4];
            #pragma unroll
            for (int mt = 0; mt < 4; ++mt) {
                const int pos = (arow[mt] + kh) * 34 + (acol[mt] + kw);
                afr[mt] = *(const short8*)&xs[buf][aq][pos][0];
            }
            #pragma unroll
            for (int mt = 0; mt < 4; ++mt)
                #pragma unroll
                for (int nt = 0; nt < 4; ++nt)
                    acc[mt][nt] = __builtin_amdgcn_mfma_f32_16x16x32_bf16(
                        afr[mt], bfr[nt], acc[mt][nt], 0, 0, 0);
            #pragma unroll
            for (int nt = 0; nt < 4; ++nt) bfr[nt] = bnx[nt];
        }
        if (cb < 8) stageX(cb + 1, buf ^ 1);
        __syncthreads();
    }

    float gv[4], bv[4], wa[4], wbv[4];
    #pragma unroll
    for (int nt = 0; nt < 4; ++nt) {
        const int co = wid * 64 + nt * 16 + am;
        gv[nt]  = g1[co];
        bv[nt]  = b1[co];
        wa[nt]  = w2[co];
        wbv[nt] = w2[256 + co];
    }
    #pragma unroll
    for (int mt = 0; mt < 4; ++mt) {
        #pragma unroll
        for (int reg = 0; reg < 4; ++reg) {
            float s0 = 0.f, s1 = 0.f;
            #pragma unroll
            for (int nt = 0; nt < 4; ++nt) {
                const float y = fmaxf(fmaf(acc[mt][nt][reg], gv[nt], bv[nt]), 0.f);
                s0 = fmaf(wa[nt], y, s0);
                s1 = fmaf(wbv[nt], y, s1);
            }
            #pragma unroll
            for (int off = 1; off < 16; off <<= 1) {
                s0 += __shfl_xor(s0, off, 64);
                s1 += __shfl_xor(s1, off, 64);
            }
            if (am == 0) {
                const int m = mt * 16 + aq * 4 + reg;
                part[wid][m][0] = s0;
                part[wid][m][1] = s1;
            }
        }
    }
    __syncthreads();
    if (tid < 64) {
        const int m = tid, r = m >> 5, c = m & 31;
        const int off = (h0 + r) * Wn + (w0 + c);
        float d0 = part[0][m][0] + part[1][m][0] + part[2][m][0] + part[3][m][0] + db2[0];
        float d1 = part[0][m][1] + part[1][m][1] + part[2][m][1] + part[3][m][1] + db2[1];
        dm_out[(size_t)(b * 2) * HWn + off]     = d0;
        dm_out[(size_t)(b * 2 + 1) * HWn + off] = d1;
        const float mx = fmaxf(d0, d1);
        const float e0 = expf(d0 - mx), e1 = expf(d1 - mx);
        const float pa = patt[b * HWn + off];
        const float inv = pa / (e0 + e1);
        s01[b * HWn + off]        = e0 * inv;
        s01[BHWn + b * HWn + off] = e1 * inv;
    }
}

// ---------------------------------------------------------------------------
extern "C" void kernel_launch(void* const* d_in, const int* in_sizes, int n_in,
                              void* d_out, int out_size, void* d_ws, size_t ws_size,
                              hipStream_t stream)
{
    (void)in_sizes; (void)n_in; (void)out_size;

    const float* f_nodes = (const float*)d_in[0];
    const float* h_nodes = (const float*)d_in[1];
    const float* p_nodes = (const float*)d_in[2];
    const float* xh      = (const float*)d_in[3];
    const float* f_atts  = (const float*)d_in[4];
    const float* p_atts  = (const float*)d_in[5];
    const float* da_w1   = (const float*)d_in[6];
    const float* da_g1   = (const float*)d_in[7];
    const float* da_b1   = (const float*)d_in[8];
    const float* da_w2   = (const float*)d_in[9];
    const float* da_b2   = (const float*)d_in[10];

    BranchW3 P;
    for (int i = 0; i < 3; ++i) {
        P.p[i].w1 = (const float*)d_in[11 + 6 * i + 0];
        P.p[i].g1 = (const float*)d_in[11 + 6 * i + 1];
        P.p[i].b1 = (const float*)d_in[11 + 6 * i + 2];
        P.p[i].w2 = (const float*)d_in[11 + 6 * i + 3];
        P.p[i].g2 = (const float*)d_in[11 + 6 * i + 4];
        P.p[i].b2 = (const float*)d_in[11 + 6 * i + 5];
    }
    const float* gru_gw = (const float*)d_in[29];
    const float* gru_gb = (const float*)d_in[30];
    const float* gru_cw = (const float*)d_in[31];
    const float* gru_cg = (const float*)d_in[32];
    const float* gru_cb = (const float*)d_in[33];

    float* out    = (float*)d_out;
    float* dm_out = out + (size_t)3 * B10HW;

    // ws layout (floats): s01[2*BHWn] | bout[4*B10HW] (wpk aliases slice 0) | xp
    float* ws   = (float*)d_ws;
    float* s01  = ws;
    float* bout = s01 + 2 * BHWn;
    short* wpk  = (short*)bout;
    const size_t XP_OFF_B = ((size_t)(2 * BHWn) + 4 * (size_t)B10HW) * 4;
    char*  xp   = (char*)d_ws + XP_OFF_B;
    const size_t WS_NEED = XP_OFF_B + (size_t)Bn * XP_OCT * XP_PLANE_BYTES;
    const bool use_packed = ws_size >= WS_NEED;

    const float* patt   = f_atts + BHWn;     // f_atts[1]
    const float* parent = f_nodes + B10HW;   // f_nodes[1]

    if (use_packed) {
        k_pack<<<dim3(PACKW_BLOCKS + 11250), 256, 0, stream>>>(da_w1, wpk, xh, patt,
                                                               (ushort*)xp);
        k_fused<<<dim3(CONV_BLOCKS + 576 + 288), 256, 0, stream>>>(
            xp, patt, wpk, da_g1, da_b1, da_w2, da_b2, dm_out, s01,
            P, parent, h_nodes, p_nodes, p_atts, bout,
            f_nodes, p_nodes, gru_gw, gru_gb, gru_cw, gru_cg, gru_cb, out);
        k_branch01<<<dim3(288, 2), 256, 0, stream>>>(P, parent, h_nodes, s01,
                                                     p_nodes, p_atts, bout);
        k_gru12<<<dim3(288, 2), 256, 0, stream>>>(f_nodes, h_nodes, p_nodes, bout,
                                                  gru_gw, gru_gb, gru_cw, gru_cg,
                                                  gru_cb, out);
    } else {
        k_packw<<<dim3(2592), 256, 0, stream>>>(da_w1, wpk);
        k_bigconv3_f<<<dim3(1152), 256, 0, stream>>>(xh, patt, wpk, da_g1, da_b1,
                                                     da_w2, da_b2, dm_out, s01);
        k_branch_all<<<dim3(288, 4), 256, 0, stream>>>(P, parent, h_nodes, s01,
                                                       p_nodes, p_atts, bout);
        k_gru_all<<<dim3(288, 3), 256, 0, stream>>>(f_nodes, h_nodes, p_nodes, bout,
                                                    gru_gw, gru_gb, gru_cw, gru_cg,
                                                    gru_cb, out);
    }
}

// Round 15
// 359.414 us; speedup vs baseline: 1.4455x; 1.4455x over previous
//
#include <hip/hip_runtime.h>
#include <cstddef>
#include <cstdint>

constexpr int Bn    = 8;
constexpr int Hn    = 96;
constexpr int Wn    = 96;
constexpr int HWn   = Hn * Wn;       // 9216
constexpr int BHWn  = Bn * HWn;      // 73728
constexpr int B10HW = Bn * 10 * HWn; // 737280

// packed-activation geometry (bf16, halo-padded, 8-channel-interleaved)
constexpr int XP_COLS        = 100;
constexpr int XP_ROWS        = 100;
constexpr int XP_PLANE       = XP_ROWS * XP_COLS; // 10000 16B groups
constexpr int XP_PLANE_BYTES = XP_PLANE * 16;     // 160000
constexpr int XP_OCT         = 36;                // 288 padded channels / 8

using short8  = __attribute__((ext_vector_type(8))) short;
using ushort8 = __attribute__((ext_vector_type(8))) unsigned short;
using float4v = __attribute__((ext_vector_type(4))) float;

__device__ __forceinline__ unsigned short f2bf(float f) {
    unsigned u = __builtin_bit_cast(unsigned, f);
    u += 0x7FFFu + ((u >> 16) & 1u);   // RNE; inputs are finite
    return (unsigned short)(u >> 16);
}

// async global->LDS: 16B per lane, LDS dest = uniform base + lane*16
__device__ __forceinline__ void async16(const void* g, void* l) {
    auto gp = (__attribute__((address_space(1))) unsigned int*)(uintptr_t)g;
    auto lp = (__attribute__((address_space(3))) unsigned int*)(unsigned)(uintptr_t)l;
    __builtin_amdgcn_global_load_lds(gp, lp, 16, 0, 0);
}

struct BranchW  { const float *w1, *g1, *b1, *w2, *g2, *b2; };
struct BranchW3 { BranchW p[3]; };

// shared-memory layouts for the fused kernel paths
struct ConvSmem   { short xs[3][4][194][8]; float part[4][64][2]; };   // 39.3 KB
struct BranchSmem {
    float xt[20][10][34];
    float paSum[340];
    float wlt[9 * 20 * 12];
    float w2l[100], g1l[10], b1l[10], g2l[10], b2l[10];
};                                                                      // 37.8 KB
struct GruSmem    { float gwl[40], cwl[200], gbl[2], cgl[10], cbl[10]; };
union FusedSmem { ConvSmem c; BranchSmem b; GruSmem g; };

// ---------------------------------------------------------------------------
// K0 (merged): bx<2592 -> pack da_w1 into B-fragment order (bf16 wpk);
// bx>=2592 -> pack activations to bf16 halo-padded xp.
// ---------------------------------------------------------------------------
constexpr int PACKW_BLOCKS = 2592;

__global__ void k_pack(const float* __restrict__ w1, short* __restrict__ wpk,
                       const float* __restrict__ xh, const float* __restrict__ patt,
                       ushort* __restrict__ xp)
{
    if (blockIdx.x < PACKW_BLOCKS) {
        const int o = blockIdx.x * 256 + threadIdx.x;   // 663552 exactly
        const int j    = o & 7;
        const int lane = (o >> 3) & 63;
        const int q    = (o >> 9) & 15;
        const int t    = o >> 13;            // 0..80 = cb*9+tap
        const int co   = q * 16 + (lane & 15);
        const int ci   = (t / 9) * 32 + ((lane >> 4) & 3) * 8 + j;
        const int tap  = t % 9;
        const float f  = (ci < 257) ? w1[((size_t)co * 257 + ci) * 9 + tap] : 0.f;
        wpk[o] = (short)f2bf(f);
    } else {
        const int g  = (blockIdx.x - PACKW_BLOCKS) * 256 + threadIdx.x; // 2,880,000
        const int cw = g % XP_COLS;
        int t = g / XP_COLS;
        const int rh = t % XP_ROWS; t /= XP_ROWS;
        const int o  = t % XP_OCT;
        const int b  = t / XP_OCT;
        const int hh = rh - 1, ww = cw - 1;
        const bool inb = ((unsigned)hh < (unsigned)Hn) & ((unsigned)ww < (unsigned)Wn);
        const int off = hh * Wn + ww;
        ushort8 v;
        #pragma unroll
        for (int j = 0; j < 8; ++j) {
            const int ci = o * 8 + j;
            float f = 0.f;
            if (inb && ci < 257)
                f = (ci == 0) ? patt[b * HWn + off]
                              : xh[((size_t)b * 256 + (ci - 1)) * HWn + off];
            v[j] = f2bf(f);
        }
        *(ushort8*)&xp[(size_t)g * 8] = v;
    }
}

// standalone packw for the fallback (no-xp) path
__global__ void k_packw(const float* __restrict__ w1, short* __restrict__ wpk)
{
    const int o = blockIdx.x * 256 + threadIdx.x;
    if (o >= 663552) return;
    const int j    = o & 7;
    const int lane = (o >> 3) & 63;
    const int q    = (o >> 9) & 15;
    const int t    = o >> 13;
    const int co   = q * 16 + (lane & 15);
    const int ci   = (t / 9) * 32 + ((lane >> 4) & 3) * 8 + j;
    const int tap  = t % 9;
    const float f  = (ci < 257) ? w1[((size_t)co * 257 + ci) * 9 + tap] : 0.f;
    wpk[o] = (short)f2bf(f);
}

// ---------------------------------------------------------------------------
// Branch body: ReLU(BN(conv3x3 20->10)) -> ReLU(BN(conv1x1 10->10)).
// z=0/1: [parent*s01, h] (rel). z=2/3: [h, composed parts] (cu/cl).
// ---------------------------------------------------------------------------
__device__ __forceinline__ void branch_body(
    BranchSmem& S, int z, int bx, int tid, const BranchW3& P,
    const float* __restrict__ parent, const float* __restrict__ h_nodes,
    const float* __restrict__ s01, const float* __restrict__ pn,
    const float* __restrict__ pa, float* __restrict__ bout)
{
    const int pi = (z < 2) ? 0 : (z - 1);
    const BranchW& Pw = P.p[pi];
    for (int idx = tid; idx < 2160; idx += 256) {
        const int co = idx % 12, rem = idx / 12, ci = rem % 20, tap = rem / 20;
        S.wlt[idx] = (co < 10) ? Pw.w1[(co * 20 + ci) * 9 + tap] : 0.f;
    }
    if (tid < 100) S.w2l[tid] = Pw.w2[tid];
    if (tid < 10) {
        S.g1l[tid] = Pw.g1[tid]; S.b1l[tid] = Pw.b1[tid];
        S.g2l[tid] = Pw.g2[tid]; S.b2l[tid] = Pw.b2[tid];
    }

    const int tw = bx % 3, th = (bx / 3) % 12, b = bx / 36;
    const int h0 = th * 8, w0 = tw * 32;

    const float* Ab;
    const float* sc = nullptr;
    const float* Bb = nullptr;
    int k0 = 0, k1 = -1;
    if (z == 0)      { Ab = parent; sc = s01;        Bb = h_nodes + (size_t)1 * B10HW; }
    else if (z == 1) { Ab = parent; sc = s01 + BHWn; Bb = h_nodes + (size_t)2 * B10HW; }
    else if (z == 2) { Ab = h_nodes + (size_t)1 * B10HW; k0 = 1; k1 = 4; }
    else             { Ab = h_nodes + (size_t)2 * B10HW; k0 = 5; k1 = 6; }

    if (z >= 2) {
        for (int idx = tid; idx < 340; idx += 256) {
            const int col = idx % 34, row = idx / 34;
            const int hh = h0 - 1 + row, ww = w0 - 1 + col;
            float s = 0.f;
            if (((unsigned)hh < (unsigned)Hn) & ((unsigned)ww < (unsigned)Wn)) {
                const int off = hh * Wn + ww;
                for (int k = k0; k <= k1; ++k)
                    s += pa[(size_t)(k * Bn + b) * HWn + off];
            }
            S.paSum[idx] = s;
        }
    }
    __syncthreads();

    for (int idx = tid; idx < 6800; idx += 256) {
        const int col = idx % 34, rem = idx / 34, row = rem % 10, ch = rem / 10;
        const int hh = h0 - 1 + row, ww = w0 - 1 + col;
        float v = 0.f;
        if (((unsigned)hh < (unsigned)Hn) & ((unsigned)ww < (unsigned)Wn)) {
            const int off = hh * Wn + ww;
            if (ch < 10) {
                v = Ab[((size_t)b * 10 + ch) * HWn + off];
                if (sc) v *= sc[b * HWn + off];
            } else if (z < 2) {
                v = Bb[((size_t)b * 10 + (ch - 10)) * HWn + off];
            } else {
                float s = 0.f;
                for (int k = k0; k <= k1; ++k)
                    s += pn[((size_t)(k * Bn + b) * 10 + (ch - 10)) * HWn + off];
                v = s * S.paSum[row * 34 + col];
            }
        }
        ((float*)S.xt)[idx] = v;
    }
    __syncthreads();

    const int r = tid >> 5, c = tid & 31;
    float a0 = 0, a1 = 0, a2 = 0, a3 = 0, a4 = 0, a5 = 0, a6 = 0, a7 = 0, a8 = 0, a9 = 0;
    #pragma unroll
    for (int tap = 0; tap < 9; ++tap) {
        const int kh = tap / 3, kw = tap % 3;
        #pragma unroll
        for (int ci = 0; ci < 20; ++ci) {
            const float xv = S.xt[ci][r + kh][c + kw];
            const float4 wA = *(const float4*)&S.wlt[(tap * 20 + ci) * 12];
            const float4 wB = *(const float4*)&S.wlt[(tap * 20 + ci) * 12 + 4];
            const float2 wC = *(const float2*)&S.wlt[(tap * 20 + ci) * 12 + 8];
            a0 = fmaf(wA.x, xv, a0); a1 = fmaf(wA.y, xv, a1);
            a2 = fmaf(wA.z, xv, a2); a3 = fmaf(wA.w, xv, a3);
            a4 = fmaf(wB.x, xv, a4); a5 = fmaf(wB.y, xv, a5);
            a6 = fmaf(wB.z, xv, a6); a7 = fmaf(wB.w, xv, a7);
            a8 = fmaf(wC.x, xv, a8); a9 = fmaf(wC.y, xv, a9);
        }
    }
    float acc[10] = {a0, a1, a2, a3, a4, a5, a6, a7, a8, a9};
    float y[10];
    #pragma unroll
    for (int co = 0; co < 10; ++co)
        y[co] = fmaxf(fmaf(acc[co], S.g1l[co], S.b1l[co]), 0.f);
    const int hw = (h0 + r) * Wn + (w0 + c);
    #pragma unroll
    for (int co = 0; co < 10; ++co) {
        float s = 0.f;
        #pragma unroll
        for (int i = 0; i < 10; ++i) s = fmaf(S.w2l[co * 10 + i], y[i], s);
        s = fmaxf(fmaf(s, S.g2l[co], S.b2l[co]), 0.f);
        bout[(size_t)z * B10HW + ((size_t)b * 10 + co) * HWn + hw] = s;
    }
}

// ---------------------------------------------------------------------------
// GRU body (1x1 ConvGRU), z = node 0/1/2.
// ---------------------------------------------------------------------------
__device__ __forceinline__ void gru_body(
    GruSmem& S, int z, int bx, int tid,
    const float* __restrict__ f_nodes, const float* __restrict__ h_nodes,
    const float* __restrict__ p_nodes, const float* __restrict__ bout,
    const float* __restrict__ gw, const float* __restrict__ gb,
    const float* __restrict__ cw, const float* __restrict__ cg,
    const float* __restrict__ cb, float* __restrict__ out)
{
    if (tid < 40)  S.gwl[tid] = gw[z * 40 + tid];
    if (tid < 200) S.cwl[tid] = cw[z * 200 + tid];
    if (tid < 2)   S.gbl[tid] = gb[z * 2 + tid];
    if (tid < 10) {
        S.cgl[tid] = cg[z * 10 + tid];
        S.cbl[tid] = cb[z * 10 + tid];
    }
    __syncthreads();

    const int p = bx * 256 + tid;
    const int b = p / HWn, hw = p % HWn;
    float x[10], h[10];
    #pragma unroll
    for (int c = 0; c < 10; ++c) {
        const size_t idx = ((size_t)b * 10 + c) * HWn + hw;
        if (z == 0)      x[c] = f_nodes[idx] + p_nodes[idx];
        else if (z == 1) x[c] = bout[(size_t)2 * B10HW + idx] + bout[idx];
        else             x[c] = bout[(size_t)3 * B10HW + idx] + bout[(size_t)1 * B10HW + idx];
        h[c] = h_nodes[(size_t)z * B10HW + idx];
    }
    float g0 = S.gbl[0], g1 = S.gbl[1];
    #pragma unroll
    for (int c = 0; c < 10; ++c) {
        g0 = fmaf(S.gwl[c],      x[c], g0);
        g0 = fmaf(S.gwl[10 + c], h[c], g0);
        g1 = fmaf(S.gwl[20 + c], x[c], g1);
        g1 = fmaf(S.gwl[30 + c], h[c], g1);
    }
    const float r = 1.f / (1.f + expf(-g0));
    const float u = 1.f / (1.f + expf(-g1));
    #pragma unroll
    for (int o = 0; o < 10; ++o) {
        float s = 0.f;
        #pragma unroll
        for (int c = 0; c < 10; ++c) {
            s = fmaf(S.cwl[o * 20 + c],      x[c],     s);
            s = fmaf(S.cwl[o * 20 + 10 + c], r * h[c], s);
        }
        s = fmaxf(fmaf(s, S.cgl[o], S.cbl[o]), 0.f);
        out[(size_t)z * B10HW + ((size_t)b * 10 + o) * HWn + hw] =
            (1.f - u) * h[o] + u * s;
    }
}

// ---------------------------------------------------------------------------
// FUSED kernel (R8 best-known, FINAL): bx<1152 = conv3x3 257->256 (+BN+ReLU+
// 1x1+softmax) with counted vmcnt(3), 3-buf LDS, setprio; launch_bounds
// (256,3) — (256,4) forced VGPR 84->64 and spilled (R14: 300 us). bx>=1152 =
// independent filler work (branch z=2/3, gru z=0) appended last.
// ---------------------------------------------------------------------------
constexpr int CONV_BLOCKS = 1152;

__global__ __launch_bounds__(256, 3)
void k_fused(const char* __restrict__ xp, const float* __restrict__ patt,
             const short* __restrict__ wpk, const float* __restrict__ g1,
             const float* __restrict__ b1, const float* __restrict__ w2,
             const float* __restrict__ db2,
             float* __restrict__ dm_out, float* __restrict__ s01,
             BranchW3 P, const float* __restrict__ parent,
             const float* __restrict__ h_nodes, const float* __restrict__ pn,
             const float* __restrict__ pa, float* __restrict__ bout,
             const float* __restrict__ f_nodes, const float* __restrict__ p_nodes,
             const float* __restrict__ gw, const float* __restrict__ gb,
             const float* __restrict__ cw, const float* __restrict__ cg,
             const float* __restrict__ cb, float* __restrict__ out)
{
    __shared__ __align__(16) FusedSmem sm;
    const int tid = threadIdx.x;
    const int bxg = blockIdx.x;

    if (bxg >= CONV_BLOCKS) {
        const int r = bxg - CONV_BLOCKS;
        if (r < 576) {
            const int z = (r < 288) ? 2 : 3;
            branch_body(sm.b, z, (r < 288) ? r : r - 288, tid, P, parent,
                        h_nodes, s01, pn, pa, bout);
        } else {
            gru_body(sm.g, 0, r - 576, tid, f_nodes, h_nodes, p_nodes, bout,
                     gw, gb, cw, cg, cb, out);
        }
        return;
    }

    const int lane = tid & 63;
    const int wid  = tid >> 6;          // wave id = n-quarter = staged octet
    const int bx   = bxg;
    const int b    = bx & 7;            // XCD-locality swizzle
    const int r2   = bx >> 3;
    const int wseg = r2 % 3;
    const int hb   = r2 / 3;
    const int h0   = hb * 2, w0 = wseg * 32;
    const int am   = lane & 15;
    const int aq   = lane >> 4;

    int poff[3];
    #pragma unroll
    for (int it = 0; it < 3; ++it) {
        const int pos = it * 64 + lane;
        const int row = pos / 34, col = pos - row * 34;
        poff[it] = ((h0 + row) * XP_COLS + (w0 + col)) * 16;
    }
    const char* xpb = xp + ((size_t)b * XP_OCT + wid) * XP_PLANE_BYTES;

    float4v acc[4][4];
    #pragma unroll
    for (int i = 0; i < 4; ++i)
        #pragma unroll
        for (int j = 0; j < 4; ++j)
            acc[i][j] = float4v{0.f, 0.f, 0.f, 0.f};

    int arow[4], acol[4];
    #pragma unroll
    for (int mt = 0; mt < 4; ++mt) {
        const int m = mt * 16 + am;
        arow[mt] = m >> 5;
        acol[mt] = m & 31;
    }

    auto stageX = [&](int cb, int buf) {
        const char* src = xpb + (size_t)cb * (4 * XP_PLANE_BYTES);
        #pragma unroll
        for (int it = 0; it < 3; ++it)
            async16(src + poff[it], &sm.c.xs[buf][wid][it * 64][0]);
    };

    const short8* wp = (const short8*)wpk;
    const int qb = wid * 4;

    auto loadB = [&](int t, short8 (&dst)[4]) {
        #pragma unroll
        for (int nt = 0; nt < 4; ++nt)
            dst[nt] = wp[((size_t)t * 16 + qb + nt) * 64 + lane];
    };

    // prologue: two chunks in flight, two B tiles in registers
    stageX(0, 0);
    stageX(1, 1);
    short8 bfr[3][4];
    loadB(0, bfr[0]);
    loadB(1, bfr[1]);

    for (int cb = 0; cb < 9; ++cb) {
        __builtin_amdgcn_sched_barrier(0);
        if (cb < 8) asm volatile("s_waitcnt vmcnt(3)" ::: "memory");
        else        asm volatile("s_waitcnt vmcnt(0)" ::: "memory");
        __builtin_amdgcn_s_barrier();
        __builtin_amdgcn_sched_barrier(0);
        if (cb < 7) stageX(cb + 2, (cb + 2) % 3);

        const int buf = cb % 3;
        #pragma unroll
        for (int tap = 0; tap < 9; ++tap) {
            const int t  = cb * 9 + tap;
            const int tl = (t + 2 <= 80) ? (t + 2) : 80;
            loadB(tl, bfr[(tap + 2) % 3]);
            const int kh = tap / 3, kw = tap % 3;
            short8 afr[4];
            #pragma unroll
            for (int mt = 0; mt < 4; ++mt) {
                const int pos = (arow[mt] + kh) * 34 + (acol[mt] + kw);
                afr[mt] = *(const short8*)&sm.c.xs[buf][aq][pos][0];
            }
            __builtin_amdgcn_s_setprio(1);
            #pragma unroll
            for (int mt = 0; mt < 4; ++mt)
                #pragma unroll
                for (int nt = 0; nt < 4; ++nt)
                    acc[mt][nt] = __builtin_amdgcn_mfma_f32_16x16x32_bf16(
                        afr[mt], bfr[tap % 3][nt], acc[mt][nt], 0, 0, 0);
            __builtin_amdgcn_s_setprio(0);
        }
    }

    float gv[4], bv[4], wa[4], wbv[4];
    #pragma unroll
    for (int nt = 0; nt < 4; ++nt) {
        const int co = wid * 64 + nt * 16 + am;
        gv[nt]  = g1[co];
        bv[nt]  = b1[co];
        wa[nt]  = w2[co];
        wbv[nt] = w2[256 + co];
    }
    #pragma unroll
    for (int mt = 0; mt < 4; ++mt) {
        #pragma unroll
        for (int reg = 0; reg < 4; ++reg) {
            float s0 = 0.f, s1 = 0.f;
            #pragma unroll
            for (int nt = 0; nt < 4; ++nt) {
                const float y = fmaxf(fmaf(acc[mt][nt][reg], gv[nt], bv[nt]), 0.f);
                s0 = fmaf(wa[nt], y, s0);
                s1 = fmaf(wbv[nt], y, s1);
            }
            #pragma unroll
            for (int off = 1; off < 16; off <<= 1) {
                s0 += __shfl_xor(s0, off, 64);
                s1 += __shfl_xor(s1, off, 64);
            }
            if (am == 0) {
                const int m = mt * 16 + aq * 4 + reg;
                sm.c.part[wid][m][0] = s0;
                sm.c.part[wid][m][1] = s1;
            }
        }
    }
    __syncthreads();
    if (tid < 64) {
        const int m = tid, r = m >> 5, c = m & 31;
        const int off = (h0 + r) * Wn + (w0 + c);
        float d0 = sm.c.part[0][m][0] + sm.c.part[1][m][0] + sm.c.part[2][m][0]
                 + sm.c.part[3][m][0] + db2[0];
        float d1 = sm.c.part[0][m][1] + sm.c.part[1][m][1] + sm.c.part[2][m][1]
                 + sm.c.part[3][m][1] + db2[1];
        dm_out[(size_t)(b * 2) * HWn + off]     = d0;
        dm_out[(size_t)(b * 2 + 1) * HWn + off] = d1;
        const float mx = fmaxf(d0, d1);
        const float e0 = expf(d0 - mx), e1 = expf(d1 - mx);
        const float pa2 = patt[b * HWn + off];
        const float inv = pa2 / (e0 + e1);
        s01[b * HWn + off]        = e0 * inv;
        s01[BHWn + b * HWn + off] = e1 * inv;
    }
}

// ---------------------------------------------------------------------------
// Remaining dependent work: branch z=0/1 (needs s01) and gru z=1/2 (needs bout)
// ---------------------------------------------------------------------------
__global__ __launch_bounds__(256)
void k_branch01(BranchW3 P, const float* __restrict__ parent,
                const float* __restrict__ h_nodes, const float* __restrict__ s01,
                const float* __restrict__ pn, const float* __restrict__ pa,
                float* __restrict__ bout)
{
    __shared__ __align__(16) BranchSmem S;
    branch_body(S, blockIdx.y, blockIdx.x, threadIdx.x, P, parent, h_nodes,
                s01, pn, pa, bout);
}

__global__ void k_gru12(const float* __restrict__ f_nodes, const float* __restrict__ h_nodes,
                        const float* __restrict__ p_nodes, const float* __restrict__ bout,
                        const float* __restrict__ gw, const float* __restrict__ gb,
                        const float* __restrict__ cw, const float* __restrict__ cg,
                        const float* __restrict__ cb, float* __restrict__ out)
{
    __shared__ GruSmem S;
    gru_body(S, blockIdx.y + 1, blockIdx.x, threadIdx.x, f_nodes, h_nodes,
             p_nodes, bout, gw, gb, cw, cg, cb, out);
}

// fallback-path full kernels
__global__ __launch_bounds__(256)
void k_branch_all(BranchW3 P, const float* __restrict__ parent,
                  const float* __restrict__ h_nodes, const float* __restrict__ s01,
                  const float* __restrict__ pn, const float* __restrict__ pa,
                  float* __restrict__ bout)
{
    __shared__ __align__(16) BranchSmem S;
    branch_body(S, blockIdx.y, blockIdx.x, threadIdx.x, P, parent, h_nodes,
                s01, pn, pa, bout);
}

__global__ void k_gru_all(const float* __restrict__ f_nodes, const float* __restrict__ h_nodes,
                          const float* __restrict__ p_nodes, const float* __restrict__ bout,
                          const float* __restrict__ gw, const float* __restrict__ gb,
                          const float* __restrict__ cw, const float* __restrict__ cg,
                          const float* __restrict__ cb, float* __restrict__ out)
{
    __shared__ GruSmem S;
    gru_body(S, blockIdx.y, blockIdx.x, threadIdx.x, f_nodes, h_nodes,
             p_nodes, bout, gw, gb, cw, cg, cb, out);
}

// ---------------------------------------------------------------------------
// K1 fallback (old staging path) — used only if ws_size can't hold xp.
// ---------------------------------------------------------------------------
__global__ __launch_bounds__(256, 3)
void k_bigconv3_f(const float* __restrict__ xh, const float* __restrict__ patt,
                  const short* __restrict__ wpk, const float* __restrict__ g1,
                  const float* __restrict__ b1, const float* __restrict__ w2,
                  const float* __restrict__ db2,
                  float* __restrict__ dm_out, float* __restrict__ s01)
{
    __shared__ __align__(16) short xs[2][4][137][8];
    __shared__ float part[4][64][2];

    const int tid  = threadIdx.x;
    const int lane = tid & 63;
    const int wid  = tid >> 6;
    const int bx   = blockIdx.x;
    const int b    = bx & 7;
    const int r2   = bx >> 3;
    const int wseg = r2 % 3;
    const int hb   = r2 / 3;
    const int h0   = hb * 2, w0 = wseg * 32;
    const int am   = lane & 15;
    const int aq   = lane >> 4;

    float4v acc[4][4];
    #pragma unroll
    for (int i = 0; i < 4; ++i)
        #pragma unroll
        for (int j = 0; j < 4; ++j)
            acc[i][j] = float4v{0.f, 0.f, 0.f, 0.f};

    int arow[4], acol[4];
    #pragma unroll
    for (int mt = 0; mt < 4; ++mt) {
        const int m = mt * 16 + am;
        arow[mt] = m >> 5;
        acol[mt] = m & 31;
    }

    auto stageX = [&](int cb, int buf) {
        const int cig0 = cb * 32 + wid * 8;
        for (int pos = lane; pos < 136; pos += 64) {
            const int row = pos / 34, col = pos % 34;
            const int hh = h0 - 1 + row, ww = w0 - 1 + col;
            const bool inb = ((unsigned)hh < (unsigned)Hn) & ((unsigned)ww < (unsigned)Wn);
            const int off = hh * Wn + ww;
            ushort8 v;
            #pragma unroll
            for (int j = 0; j < 8; ++j) {
                const int ci = cig0 + j;
                float f = 0.f;
                if (inb && ci < 257)
                    f = (ci == 0) ? patt[b * HWn + off]
                                  : xh[((size_t)b * 256 + (ci - 1)) * HWn + off];
                v[j] = f2bf(f);
            }
            *(ushort8*)&xs[buf][wid][pos][0] = v;
        }
    };

    const short8* wp = (const short8*)wpk;
    const int qb = wid * 4;

    stageX(0, 0);
    short8 bfr[4], bnx[4];
    #pragma unroll
    for (int nt = 0; nt < 4; ++nt)
        bfr[nt] = wp[(size_t)(qb + nt) * 64 + lane];
    __syncthreads();

    for (int cb = 0; cb < 9; ++cb) {
        const int buf = cb & 1;
        for (int tap = 0; tap < 9; ++tap) {
            const int t = cb * 9 + tap;
            if (t < 80) {
                #pragma unroll
                for (int nt = 0; nt < 4; ++nt)
                    bnx[nt] = wp[((size_t)(t + 1) * 16 + qb + nt) * 64 + lane];
            }
            const int kh = tap / 3, kw = tap % 3;
            short8 afr[4];
            #pragma unroll
            for (int mt = 0; mt < 4; ++mt) {
                const int pos = (arow[mt] + kh) * 34 + (acol[mt] + kw);
                afr[mt] = *(const short8*)&xs[buf][aq][pos][0];
            }
            #pragma unroll
            for (int mt = 0; mt < 4; ++mt)
                #pragma unroll
                for (int nt = 0; nt < 4; ++nt)
                    acc[mt][nt] = __builtin_amdgcn_mfma_f32_16x16x32_bf16(
                        afr[mt], bfr[nt], acc[mt][nt], 0, 0, 0);
            #pragma unroll
            for (int nt = 0; nt < 4; ++nt) bfr[nt] = bnx[nt];
        }
        if (cb < 8) stageX(cb + 1, buf ^ 1);
        __syncthreads();
    }

    float gv[4], bv[4], wa[4], wbv[4];
    #pragma unroll
    for (int nt = 0; nt < 4; ++nt) {
        const int co = wid * 64 + nt * 16 + am;
        gv[nt]  = g1[co];
        bv[nt]  = b1[co];
        wa[nt]  = w2[co];
        wbv[nt] = w2[256 + co];
    }
    #pragma unroll
    for (int mt = 0; mt < 4; ++mt) {
        #pragma unroll
        for (int reg = 0; reg < 4; ++reg) {
            float s0 = 0.f, s1 = 0.f;
            #pragma unroll
            for (int nt = 0; nt < 4; ++nt) {
                const float y = fmaxf(fmaf(acc[mt][nt][reg], gv[nt], bv[nt]), 0.f);
                s0 = fmaf(wa[nt], y, s0);
                s1 = fmaf(wbv[nt], y, s1);
            }
            #pragma unroll
            for (int off = 1; off < 16; off <<= 1) {
                s0 += __shfl_xor(s0, off, 64);
                s1 += __shfl_xor(s1, off, 64);
            }
            if (am == 0) {
                const int m = mt * 16 + aq * 4 + reg;
                part[wid][m][0] = s0;
                part[wid][m][1] = s1;
            }
        }
    }
    __syncthreads();
    if (tid < 64) {
        const int m = tid, r = m >> 5, c = m & 31;
        const int off = (h0 + r) * Wn + (w0 + c);
        float d0 = part[0][m][0] + part[1][m][0] + part[2][m][0] + part[3][m][0] + db2[0];
        float d1 = part[0][m][1] + part[1][m][1] + part[2][m][1] + part[3][m][1] + db2[1];
        dm_out[(size_t)(b * 2) * HWn + off]     = d0;
        dm_out[(size_t)(b * 2 + 1) * HWn + off] = d1;
        const float mx = fmaxf(d0, d1);
        const float e0 = expf(d0 - mx), e1 = expf(d1 - mx);
        const float pa = patt[b * HWn + off];
        const float inv = pa / (e0 + e1);
        s01[b * HWn + off]        = e0 * inv;
        s01[BHWn + b * HWn + off] = e1 * inv;
    }
}

// ---------------------------------------------------------------------------
extern "C" void kernel_launch(void* const* d_in, const int* in_sizes, int n_in,
                              void* d_out, int out_size, void* d_ws, size_t ws_size,
                              hipStream_t stream)
{
    (void)in_sizes; (void)n_in; (void)out_size;

    const float* f_nodes = (const float*)d_in[0];
    const float* h_nodes = (const float*)d_in[1];
    const float* p_nodes = (const float*)d_in[2];
    const float* xh      = (const float*)d_in[3];
    const float* f_atts  = (const float*)d_in[4];
    const float* p_atts  = (const float*)d_in[5];
    const float* da_w1   = (const float*)d_in[6];
    const float* da_g1   = (const float*)d_in[7];
    const float* da_b1   = (const float*)d_in[8];
    const float* da_w2   = (const float*)d_in[9];
    const float* da_b2   = (const float*)d_in[10];

    BranchW3 P;
    for (int i = 0; i < 3; ++i) {
        P.p[i].w1 = (const float*)d_in[11 + 6 * i + 0];
        P.p[i].g1 = (const float*)d_in[11 + 6 * i + 1];
        P.p[i].b1 = (const float*)d_in[11 + 6 * i + 2];
        P.p[i].w2 = (const float*)d_in[11 + 6 * i + 3];
        P.p[i].g2 = (const float*)d_in[11 + 6 * i + 4];
        P.p[i].b2 = (const float*)d_in[11 + 6 * i + 5];
    }
    const float* gru_gw = (const float*)d_in[29];
    const float* gru_gb = (const float*)d_in[30];
    const float* gru_cw = (const float*)d_in[31];
    const float* gru_cg = (const float*)d_in[32];
    const float* gru_cb = (const float*)d_in[33];

    float* out    = (float*)d_out;
    float* dm_out = out + (size_t)3 * B10HW;

    // ws layout (floats): s01[2*BHWn] | bout[4*B10HW] (wpk aliases slice 0) | xp
    float* ws   = (float*)d_ws;
    float* s01  = ws;
    float* bout = s01 + 2 * BHWn;
    short* wpk  = (short*)bout;
    const size_t XP_OFF_B = ((size_t)(2 * BHWn) + 4 * (size_t)B10HW) * 4;
    char*  xp   = (char*)d_ws + XP_OFF_B;
    const size_t WS_NEED = XP_OFF_B + (size_t)Bn * XP_OCT * XP_PLANE_BYTES;
    const bool use_packed = ws_size >= WS_NEED;

    const float* patt   = f_atts + BHWn;     // f_atts[1]
    const float* parent = f_nodes + B10HW;   // f_nodes[1]

    if (use_packed) {
        k_pack<<<dim3(PACKW_BLOCKS + 11250), 256, 0, stream>>>(da_w1, wpk, xh, patt,
                                                               (ushort*)xp);
        k_fused<<<dim3(CONV_BLOCKS + 576 + 288), 256, 0, stream>>>(
            xp, patt, wpk, da_g1, da_b1, da_w2, da_b2, dm_out, s01,
            P, parent, h_nodes, p_nodes, p_atts, bout,
            f_nodes, p_nodes, gru_gw, gru_gb, gru_cw, gru_cg, gru_cb, out);
        k_branch01<<<dim3(288, 2), 256, 0, stream>>>(P, parent, h_nodes, s01,
                                                     p_nodes, p_atts, bout);
        k_gru12<<<dim3(288, 2), 256, 0, stream>>>(f_nodes, h_nodes, p_nodes, bout,
                                                  gru_gw, gru_gb, gru_cw, gru_cg,
                                                  gru_cb, out);
    } else {
        k_packw<<<dim3(2592), 256, 0, stream>>>(da_w1, wpk);
        k_bigconv3_f<<<dim3(1152), 256, 0, stream>>>(xh, patt, wpk, da_g1, da_b1,
                                                     da_w2, da_b2, dm_out, s01);
        k_branch_all<<<dim3(288, 4), 256, 0, stream>>>(P, parent, h_nodes, s01,
                                                       p_nodes, p_atts, bout);
        k_gru_all<<<dim3(288, 3), 256, 0, stream>>>(f_nodes, h_nodes, p_nodes, bout,
                                                    gru_gw, gru_gb, gru_cw, gru_cg,
                                                    gru_cb, out);
    }
}